// Round 14
// baseline (399.389 us; speedup 1.0000x reference)
//
#include <hip/hip_runtime.h>
#include <hip/hip_fp16.h>
#include <math.h>

#define N_NODES 100000
#define N_EDGES 1000000
#define D_MODEL 128
#define EDGE_DIM 64
#define SCHUNK 250
#define NSB 400

typedef short bf16x8 __attribute__((ext_vector_type(8)));
typedef float f32x4 __attribute__((ext_vector_type(4)));
typedef float f32x2 __attribute__((ext_vector_type(2)));

__device__ __forceinline__ short f2bf(float f) {
    union { float f; unsigned u; } v; v.f = f;
    unsigned r = v.u + 0x7FFFu + ((v.u >> 16) & 1u);
    return (short)(r >> 16);
}
// tanh-form GELU: max abs dev ~4e-4
__device__ __forceinline__ float gelu_fast(float x) {
    float t = 0.7978845608028654f * x * (1.0f + 0.044715f * x * x);
    float e = __expf(2.0f * t);
    return x * (1.0f - __builtin_amdgcn_rcpf(e + 1.0f));
}
__device__ __forceinline__ float sigmoid_fast(float x) {
    return __builtin_amdgcn_rcpf(1.0f + __expf(-x));
}
__device__ __forceinline__ float bflo(unsigned v) { return __uint_as_float(v << 16); }
__device__ __forceinline__ float bfhi(unsigned v) { return __uint_as_float(v & 0xFFFF0000u); }
__device__ __forceinline__ bf16x8 cvt8(float4 v0, float4 v1) {
    bf16x8 t;
    t[0] = f2bf(v0.x); t[1] = f2bf(v0.y); t[2] = f2bf(v0.z); t[3] = f2bf(v0.w);
    t[4] = f2bf(v1.x); t[5] = f2bf(v1.y); t[6] = f2bf(v1.z); t[7] = f2bf(v1.w);
    return t;
}

// ---- fp8 e4m3fn encode/decode (HW path on gfx950; manual fallback otherwise)
#if __has_builtin(__builtin_amdgcn_cvt_pk_fp8_f32) && __has_builtin(__builtin_amdgcn_cvt_pk_f32_fp8)
__device__ __forceinline__ unsigned char fp8_enc(float f) {
    int p = __builtin_amdgcn_cvt_pk_fp8_f32(f, f, 0, false);
    return (unsigned char)(p & 0xFF);
}
template <bool HI>
__device__ __forceinline__ f32x2 fp8_dec2(unsigned dw) {
    return __builtin_amdgcn_cvt_pk_f32_fp8((int)dw, HI);
}
#else
__device__ __forceinline__ unsigned char fp8_enc(float f) {
    unsigned su = (__float_as_uint(f) >> 24) & 0x80u;
    float af = fminf(fabsf(f), 448.0f);
    unsigned u = __float_as_uint(af);
    int e = (int)((u >> 23) & 255) - 120;
    unsigned b;
    if (e <= 0) b = (unsigned)__float2int_rn(af * 512.0f);
    else {
        unsigned m = (u >> 20) & 7u;
        unsigned rnd = (u >> 19) & 1u;
        b = (((unsigned)e << 3) | m) + rnd;
    }
    b = min(b, 126u);
    return (unsigned char)(su | b);
}
__device__ __forceinline__ float fp8d1(unsigned b) {
    unsigned s = (b & 0x80u) << 24;
    unsigned em = b & 0x7Fu;
    float mag;
    if (em >= 8) mag = __uint_as_float((((em >> 3) + 120u) << 23) | ((em & 7u) << 20));
    else mag = (float)em * 0.001953125f;
    return __uint_as_float(s | __float_as_uint(mag));
}
template <bool HI>
__device__ __forceinline__ f32x2 fp8_dec2(unsigned dw) {
    unsigned w = HI ? (dw >> 16) : dw;
    f32x2 r; r[0] = fp8d1(w & 0xFFu); r[1] = fp8d1((w >> 8) & 0xFFu);
    return r;
}
#endif

// ---------------- one-shot: bf16 B-fragment tables for W_src, W_dst, Wg1 + zero deg
// frag layout: [kb][nt][lane][e] ; value = W[kb*32 + (lane>>4)*8 + e][nt*16 + (lane&15)]
__global__ __launch_bounds__(256) void k_prep(
    const float* __restrict__ Ws, const float* __restrict__ Wd,
    const float* __restrict__ Wg1, short* __restrict__ frag,
    int* __restrict__ deg)
{
    int b = blockIdx.x;
    if (b >= 20) {  // zero-deg portion
        int i = (b - 20) * 256 + threadIdx.x;
        if (i < N_NODES) deg[i] = 0;
        return;
    }
    int g = b * 256 + threadIdx.x;
    if (g >= 5120) return;
    const float* W; short* T; int q;
    if (g < 2048)      { W = Ws;  T = frag;         q = g; }
    else if (g < 4096) { W = Wd;  T = frag + 16384; q = g - 2048; }
    else               { W = Wg1; T = frag + 32768; q = g - 4096; }
    int ls = q & 63, nt = (q >> 6) & 7, kb = q >> 9;
    int col = nt * 16 + (ls & 15);
    int k0 = kb * 32 + (ls >> 4) * 8;
    bf16x8 v;
    #pragma unroll
    for (int e = 0; e < 8; ++e) v[e] = f2bf(W[(k0 + e) * D_MODEL + col]);
    *reinterpret_cast<bf16x8*>(T + (size_t)q * 8) = v;
}

// ---------------- degree count; atomic return value = rank of edge within its dst
__global__ void k_deg(const int* __restrict__ dst, int* __restrict__ deg, int* __restrict__ rank) {
    int e = blockIdx.x * 256 + threadIdx.x;
    if (e < N_EDGES) rank[e] = atomicAdd(&deg[dst[e]], 1);
}

// ---------------- 3-stage exclusive scan -> rstart (with rstart[N]=E sentinel)
__global__ __launch_bounds__(256) void k_scan1(const int* __restrict__ deg, int* __restrict__ bsum) {
    __shared__ int s[256];
    int tid = threadIdx.x;
    int i = blockIdx.x * SCHUNK + tid;
    int v = (tid < SCHUNK && i < N_NODES) ? deg[i] : 0;
    s[tid] = v; __syncthreads();
    for (int off = 128; off > 0; off >>= 1) {
        if (tid < off) s[tid] += s[tid + off];
        __syncthreads();
    }
    if (tid == 0) bsum[blockIdx.x] = s[0];
}
__global__ __launch_bounds__(512) void k_scan2(const int* __restrict__ bsum, int* __restrict__ boff) {
    __shared__ int s[512];
    int tid = threadIdx.x;
    int v = (tid < NSB) ? bsum[tid] : 0;
    s[tid] = v; __syncthreads();
    for (int off = 1; off < 512; off <<= 1) {
        int t = (tid >= off) ? s[tid - off] : 0;
        __syncthreads();
        s[tid] += t;
        __syncthreads();
    }
    if (tid < NSB) boff[tid] = s[tid] - v;
}
__global__ __launch_bounds__(256) void k_scan3(const int* __restrict__ deg, const int* __restrict__ boff,
                                               int* __restrict__ rstart) {
    __shared__ int s[256];
    int tid = threadIdx.x;
    int i = blockIdx.x * SCHUNK + tid;
    int v = (tid < SCHUNK && i < N_NODES) ? deg[i] : 0;
    s[tid] = v; __syncthreads();
    for (int off = 1; off < 256; off <<= 1) {
        int t = (tid >= off) ? s[tid - off] : 0;
        __syncthreads();
        s[tid] += t;
        __syncthreads();
    }
    int excl = s[tid] - v;
    if (tid < SCHUNK && i < N_NODES) {
        rstart[i] = boff[blockIdx.x] + excl;
        if (i == N_NODES - 1) rstart[N_NODES] = boff[blockIdx.x] + excl + v;  // = N_EDGES
    }
}

// ---------------- y_src = fp8(x_src@W_src), z_bf = bf16(x_dst@W_dst + b_dst)
__global__ __launch_bounds__(256, 3) void k_node_linear(
    const float* __restrict__ x_src, const float* __restrict__ x_dst,
    const short* __restrict__ WsrcF, const short* __restrict__ WdstF,
    const float* __restrict__ b_dst,
    unsigned char* __restrict__ ysrc, short* __restrict__ z_bf)
{
    __shared__ __align__(16) short Bf[4][8][64][8];  // 32 KB
    const int tid = threadIdx.x;
    const int lane = tid & 63;
    const int wid = tid >> 6;
    const int l15 = lane & 15;
    const int lg = lane >> 4;
    const int mat = blockIdx.y;
    const float* __restrict__ X = mat ? x_dst : x_src;
    const short* __restrict__ WF = mat ? WdstF : WsrcF;
    const int row0 = blockIdx.x * 128 + wid * 32;

    const float* rowp[2];
    #pragma unroll
    for (int st = 0; st < 2; ++st) {
        int r = min(row0 + st * 16 + l15, N_NODES - 1);
        rowp[st] = X + (size_t)r * D_MODEL + lg * 8;
    }

    float4 buf[2][2][2];
    #pragma unroll
    for (int st = 0; st < 2; ++st) {
        buf[0][st][0] = *reinterpret_cast<const float4*>(rowp[st]);
        buf[0][st][1] = *reinterpret_cast<const float4*>(rowp[st] + 4);
    }

    #pragma unroll
    for (int i = 0; i < 8; ++i)
        reinterpret_cast<int4*>(Bf)[tid + i * 256] =
            reinterpret_cast<const int4*>(WF)[tid + i * 256];

    f32x4 acc[2][8];
    #pragma unroll
    for (int st = 0; st < 2; ++st)
        #pragma unroll
        for (int nt = 0; nt < 8; ++nt) { f32x4 zz = {0.f,0.f,0.f,0.f}; acc[st][nt] = zz; }

    __syncthreads();

    #pragma unroll
    for (int kb = 0; kb < 4; ++kb) {
        if (kb < 3) {
            #pragma unroll
            for (int st = 0; st < 2; ++st) {
                buf[(kb + 1) & 1][st][0] = *reinterpret_cast<const float4*>(rowp[st] + (kb + 1) * 32);
                buf[(kb + 1) & 1][st][1] = *reinterpret_cast<const float4*>(rowp[st] + (kb + 1) * 32 + 4);
            }
        }
        bf16x8 a[2];
        #pragma unroll
        for (int st = 0; st < 2; ++st)
            a[st] = cvt8(buf[kb & 1][st][0], buf[kb & 1][st][1]);
        #pragma unroll
        for (int nt = 0; nt < 8; ++nt) {
            bf16x8 b = *reinterpret_cast<const bf16x8*>(&Bf[kb][nt][lane][0]);
            acc[0][nt] = __builtin_amdgcn_mfma_f32_16x16x32_bf16(a[0], b, acc[0][nt], 0, 0, 0);
            acc[1][nt] = __builtin_amdgcn_mfma_f32_16x16x32_bf16(a[1], b, acc[1][nt], 0, 0, 0);
        }
    }

    #pragma unroll
    for (int st = 0; st < 2; ++st) {
        int rowb = row0 + st * 16 + lg * 4;
        #pragma unroll
        for (int nt = 0; nt < 8; ++nt) {
            int col = nt * 16 + l15;
            float bias = mat ? b_dst[col] : 0.0f;
            #pragma unroll
            for (int r = 0; r < 4; ++r) {
                int row = rowb + r;
                if (row < N_NODES) {
                    float v = acc[st][nt][r];
                    if (mat) z_bf[(size_t)row * D_MODEL + col] = f2bf(v + bias);
                    else     ysrc[(size_t)row * D_MODEL + col] = fp8_enc(v);
                }
            }
        }
    }
}

// ---------------- gate MLP + atomic-free CSR scatter
// 256 edges per block (2 tiles of 128) sharing ONE staged Wg1F LDS table
__global__ __launch_bounds__(256, 5) void k_gate_fill(
    const float* __restrict__ ea, const short* __restrict__ Wg1F,
    const float* __restrict__ bg1, const float* __restrict__ Wg2,
    const float* __restrict__ bg2,
    const int* __restrict__ dstI, const int* __restrict__ srcI,
    const int* __restrict__ rank, const int* __restrict__ rstart,
    int2* __restrict__ sg)
{
    __shared__ __align__(16) short Bf[2][8][64][8];  // 16 KB
    const int tid = threadIdx.x;
    const int lane = tid & 63;
    const int wid = tid >> 6;
    const int l15 = lane & 15;
    const int lg = lane >> 4;

    // stage Wg1 fragment table once for both tiles
    #pragma unroll
    for (int i = 0; i < 4; ++i)
        reinterpret_cast<int4*>(Bf)[tid + i * 256] =
            reinterpret_cast<const int4*>(Wg1F)[tid + i * 256];
    __syncthreads();

    for (int half = 0; half < 2; ++half) {
        const int e0 = blockIdx.x * 256 + half * 128 + wid * 32;

        const float* rp[2];
        #pragma unroll
        for (int st = 0; st < 2; ++st) {
            int r = min(e0 + st * 16 + l15, N_EDGES - 1);
            rp[st] = ea + (size_t)r * EDGE_DIM + lg * 8;
        }
        float4 b0[2][2], b1[2][2];
        #pragma unroll
        for (int st = 0; st < 2; ++st) {
            b0[st][0] = *reinterpret_cast<const float4*>(rp[st]);
            b0[st][1] = *reinterpret_cast<const float4*>(rp[st] + 4);
            b1[st][0] = *reinterpret_cast<const float4*>(rp[st] + 32);
            b1[st][1] = *reinterpret_cast<const float4*>(rp[st] + 36);
        }

        bf16x8 aA[2], aB[2];
        #pragma unroll
        for (int st = 0; st < 2; ++st) aA[st] = cvt8(b0[st][0], b0[st][1]);
        #pragma unroll
        for (int st = 0; st < 2; ++st) aB[st] = cvt8(b1[st][0], b1[st][1]);

        float part[2][4] = {{0.f,0.f,0.f,0.f},{0.f,0.f,0.f,0.f}};
        #pragma unroll
        for (int ntc = 0; ntc < 2; ++ntc) {
            f32x4 acc[2][4];
            #pragma unroll
            for (int st = 0; st < 2; ++st)
                #pragma unroll
                for (int nt = 0; nt < 4; ++nt) { f32x4 zz = {0.f,0.f,0.f,0.f}; acc[st][nt] = zz; }
            #pragma unroll
            for (int nt = 0; nt < 4; ++nt) {
                bf16x8 b = *reinterpret_cast<const bf16x8*>(&Bf[0][ntc * 4 + nt][lane][0]);
                acc[0][nt] = __builtin_amdgcn_mfma_f32_16x16x32_bf16(aA[0], b, acc[0][nt], 0, 0, 0);
                acc[1][nt] = __builtin_amdgcn_mfma_f32_16x16x32_bf16(aA[1], b, acc[1][nt], 0, 0, 0);
            }
            #pragma unroll
            for (int nt = 0; nt < 4; ++nt) {
                bf16x8 b = *reinterpret_cast<const bf16x8*>(&Bf[1][ntc * 4 + nt][lane][0]);
                acc[0][nt] = __builtin_amdgcn_mfma_f32_16x16x32_bf16(aB[0], b, acc[0][nt], 0, 0, 0);
                acc[1][nt] = __builtin_amdgcn_mfma_f32_16x16x32_bf16(aB[1], b, acc[1][nt], 0, 0, 0);
            }
            #pragma unroll
            for (int nt = 0; nt < 4; ++nt) {
                int col = (ntc * 4 + nt) * 16 + l15;
                float b1c = bg1[col];
                float w2 = Wg2[col];
                #pragma unroll
                for (int st = 0; st < 2; ++st)
                    #pragma unroll
                    for (int r = 0; r < 4; ++r)
                        part[st][r] += gelu_fast(acc[st][nt][r] + b1c) * w2;
            }
        }

        #pragma unroll
        for (int m = 1; m <= 8; m <<= 1)
            #pragma unroll
            for (int st = 0; st < 2; ++st)
                #pragma unroll
                for (int r = 0; r < 4; ++r)
                    part[st][r] += __shfl_xor(part[st][r], m);

        if (l15 == 0) {
            float b2 = bg2[0];
            #pragma unroll
            for (int st = 0; st < 2; ++st)
                #pragma unroll
                for (int r = 0; r < 4; ++r) {
                    int e = e0 + st * 16 + lg * 4 + r;
                    if (e < N_EDGES) {
                        float gv = sigmoid_fast(part[st][r] + b2);
                        int d = dstI[e];
                        int p = rstart[d] + rank[e];
                        int2 v; v.x = srcI[e]; v.y = __float_as_int(gv);
                        sg[p] = v;
                    }
                }
        }
    }
}

// ---------------- per-node gather + mean + residual + LN + GELU
// one wave per node; 16 lanes per fp8 edge row (uint2 = 8 fp8/lane), 4 edges in flight
__global__ __launch_bounds__(256) void k_agg(
    const int* __restrict__ rstart, const int2* __restrict__ sg,
    const unsigned char* __restrict__ ysrc, const short* __restrict__ z_bf,
    const float* __restrict__ gamma, const float* __restrict__ beta,
    float* __restrict__ out)
{
    const int lane = threadIdx.x & 63;
    const int wid = threadIdx.x >> 6;
    const int n = blockIdx.x * 4 + wid;
    const int l15 = lane & 15;
    const int lg = lane >> 4;
    const int d0 = l15 * 8;
    const int start = rstart[n];
    const int end = rstart[n + 1];
    const int dg = end - start;

    // node-constant loads issued early
    uint4 zv = *reinterpret_cast<const uint4*>(&z_bf[(size_t)n * D_MODEL + d0]);
    float4 gA = *reinterpret_cast<const float4*>(&gamma[d0]);
    float4 gB = *reinterpret_cast<const float4*>(&gamma[d0 + 4]);
    float4 bA = *reinterpret_cast<const float4*>(&beta[d0]);
    float4 bB = *reinterpret_cast<const float4*>(&beta[d0 + 4]);

    float a[8];
    #pragma unroll
    for (int j = 0; j < 8; ++j) a[j] = 0.f;

    int t = start + lg;
    bool v = t < end;
    int2 eC = make_int2(0, 0); uint2 pC = make_uint2(0, 0);
    if (v) {
        eC = sg[t];
        pC = *reinterpret_cast<const uint2*>(&ysrc[(size_t)eC.x * D_MODEL + d0]);
    }
    while (v) {
        int t2 = t + 4;
        bool v2 = t2 < end;
        int2 eN = make_int2(0, 0); uint2 pN = make_uint2(0, 0);
        if (v2) {
            eN = sg[t2];
            pN = *reinterpret_cast<const uint2*>(&ysrc[(size_t)eN.x * D_MODEL + d0]);
        }
        float g = __int_as_float(eC.y);
        f32x2 q0 = fp8_dec2<false>(pC.x);
        f32x2 q1 = fp8_dec2<true>(pC.x);
        f32x2 q2 = fp8_dec2<false>(pC.y);
        f32x2 q3 = fp8_dec2<true>(pC.y);
        a[0] += g * q0[0]; a[1] += g * q0[1];
        a[2] += g * q1[0]; a[3] += g * q1[1];
        a[4] += g * q2[0]; a[5] += g * q2[1];
        a[6] += g * q3[0]; a[7] += g * q3[1];
        t = t2; eC = eN; pC = pN; v = v2;
    }

    // combine the 4 lg replicas
    #pragma unroll
    for (int j = 0; j < 8; ++j) {
        a[j] += __shfl_xor(a[j], 16);
        a[j] += __shfl_xor(a[j], 32);
    }

    float inv = 1.0f / fmaxf((float)dg, 1.0f);
    float tv[8];
    tv[0] = a[0] * inv + bflo(zv.x); tv[1] = a[1] * inv + bfhi(zv.x);
    tv[2] = a[2] * inv + bflo(zv.y); tv[3] = a[3] * inv + bfhi(zv.y);
    tv[4] = a[4] * inv + bflo(zv.z); tv[5] = a[5] * inv + bfhi(zv.z);
    tv[6] = a[6] * inv + bflo(zv.w); tv[7] = a[7] * inv + bfhi(zv.w);

    float s = 0.f;
    #pragma unroll
    for (int j = 0; j < 8; ++j) s += tv[j];
    #pragma unroll
    for (int m = 1; m <= 8; m <<= 1) s += __shfl_xor(s, m);
    float mu = s * (1.0f / 128.0f);

    float vs = 0.f;
    float dv[8];
    #pragma unroll
    for (int j = 0; j < 8; ++j) { dv[j] = tv[j] - mu; vs += dv[j] * dv[j]; }
    #pragma unroll
    for (int m = 1; m <= 8; m <<= 1) vs += __shfl_xor(vs, m);
    float rstd = rsqrtf(vs * (1.0f / 128.0f) + 1e-5f);

    float o[8];
    o[0] = gelu_fast(dv[0] * rstd * gA.x + bA.x);
    o[1] = gelu_fast(dv[1] * rstd * gA.y + bA.y);
    o[2] = gelu_fast(dv[2] * rstd * gA.z + bA.z);
    o[3] = gelu_fast(dv[3] * rstd * gA.w + bA.w);
    o[4] = gelu_fast(dv[4] * rstd * gB.x + bB.x);
    o[5] = gelu_fast(dv[5] * rstd * gB.y + bB.y);
    o[6] = gelu_fast(dv[6] * rstd * gB.z + bB.z);
    o[7] = gelu_fast(dv[7] * rstd * gB.w + bB.w);

    if (lg == 0) {
        float4 w = make_float4(o[0], o[1], o[2], o[3]);
        *reinterpret_cast<float4*>(&out[(size_t)n * D_MODEL + d0]) = w;
    } else if (lg == 1) {
        float4 w = make_float4(o[4], o[5], o[6], o[7]);
        *reinterpret_cast<float4*>(&out[(size_t)n * D_MODEL + d0 + 4]) = w;
    }
}

extern "C" void kernel_launch(void* const* d_in, const int* in_sizes, int n_in,
                              void* d_out, int out_size, void* d_ws, size_t ws_size,
                              hipStream_t stream)
{
    const float* x_src = (const float*)d_in[0];
    const float* x_dst = (const float*)d_in[1];
    const float* ea    = (const float*)d_in[2];
    const int*   ei    = (const int*)d_in[3];
    const float* W_src = (const float*)d_in[4];
    const float* W_dst = (const float*)d_in[5];
    const float* b_dst = (const float*)d_in[6];
    const float* Wg1   = (const float*)d_in[7];
    const float* bg1   = (const float*)d_in[8];
    const float* Wg2   = (const float*)d_in[9];
    const float* bg2   = (const float*)d_in[10];
    const float* gamma = (const float*)d_in[11];
    const float* beta  = (const float*)d_in[12];
    const int* srcIdx = ei;
    const int* dstIdx = ei + N_EDGES;

    char* ws = (char*)d_ws;
    short*         fragT  = (short*)(ws);                    //     81,920 B
    unsigned char* ysrc   = (unsigned char*)(ws + 81920);    // 12,800,000 B (fp8)
    short*         z_bf   = (short*)(ws + 12881920);         // 25,600,000 B
    int*           deg    = (int*)(ws + 38481920);           //    400,000 B
    int*           rank   = (int*)(ws + 38881920);           //  4,000,000 B
    int*           rstart = (int*)(ws + 42881920);           //    400,004 B
    int2*          sg     = (int2*)(ws + 43281928);          //  8,000,000 B
    int*           bsum   = (int*)(ws + 51281928);           //      1,600 B
    int*           boff   = (int*)(ws + 51283528);           //      1,600 B

    float* out = (float*)d_out;

    hipLaunchKernelGGL(k_prep, dim3(411), dim3(256), 0, stream, W_src, W_dst, Wg1, fragT, deg);
    hipLaunchKernelGGL(k_deg, dim3(3907), dim3(256), 0, stream, dstIdx, deg, rank);
    hipLaunchKernelGGL(k_scan1, dim3(NSB), dim3(256), 0, stream, deg, bsum);
    hipLaunchKernelGGL(k_scan2, dim3(1), dim3(512), 0, stream, bsum, boff);
    hipLaunchKernelGGL(k_scan3, dim3(NSB), dim3(256), 0, stream, deg, boff, rstart);
    hipLaunchKernelGGL(k_node_linear, dim3(782, 2), dim3(256), 0, stream,
                       x_src, x_dst, fragT, fragT + 16384, b_dst, ysrc, z_bf);
    hipLaunchKernelGGL(k_gate_fill, dim3(3907), dim3(256), 0, stream,
                       ea, fragT + 32768, bg1, Wg2, bg2, dstIdx, srcIdx, rank, rstart, sg);
    hipLaunchKernelGGL(k_agg, dim3(N_NODES / 4), dim3(256), 0, stream,
                       rstart, sg, ysrc, z_bf, gamma, beta, out);
}

// Round 15
// 250.697 us; speedup vs baseline: 1.5931x; 1.5931x over previous
//
#include <hip/hip_runtime.h>
#include <hip/hip_fp16.h>
#include <math.h>

#define N_NODES 100000
#define N_EDGES 1000000
#define D_MODEL 128
#define EDGE_DIM 64
#define SCHUNK 250
#define NSB 400

typedef short bf16x8 __attribute__((ext_vector_type(8)));
typedef float f32x4 __attribute__((ext_vector_type(4)));
typedef float f32x2 __attribute__((ext_vector_type(2)));

__device__ __forceinline__ short f2bf(float f) {
    union { float f; unsigned u; } v; v.f = f;
    unsigned r = v.u + 0x7FFFu + ((v.u >> 16) & 1u);
    return (short)(r >> 16);
}
// tanh-form GELU: max abs dev ~4e-4
__device__ __forceinline__ float gelu_fast(float x) {
    float t = 0.7978845608028654f * x * (1.0f + 0.044715f * x * x);
    float e = __expf(2.0f * t);
    return x * (1.0f - __builtin_amdgcn_rcpf(e + 1.0f));
}
__device__ __forceinline__ float sigmoid_fast(float x) {
    return __builtin_amdgcn_rcpf(1.0f + __expf(-x));
}
__device__ __forceinline__ float bflo(unsigned v) { return __uint_as_float(v << 16); }
__device__ __forceinline__ float bfhi(unsigned v) { return __uint_as_float(v & 0xFFFF0000u); }
__device__ __forceinline__ bf16x8 cvt8(float4 v0, float4 v1) {
    bf16x8 t;
    t[0] = f2bf(v0.x); t[1] = f2bf(v0.y); t[2] = f2bf(v0.z); t[3] = f2bf(v0.w);
    t[4] = f2bf(v1.x); t[5] = f2bf(v1.y); t[6] = f2bf(v1.z); t[7] = f2bf(v1.w);
    return t;
}

// ---- fp8 e4m3fn encode/decode (HW path on gfx950; manual fallback otherwise)
#if __has_builtin(__builtin_amdgcn_cvt_pk_fp8_f32) && __has_builtin(__builtin_amdgcn_cvt_pk_f32_fp8)
__device__ __forceinline__ unsigned char fp8_enc(float f) {
    int p = __builtin_amdgcn_cvt_pk_fp8_f32(f, f, 0, false);
    return (unsigned char)(p & 0xFF);
}
template <bool HI>
__device__ __forceinline__ f32x2 fp8_dec2(unsigned dw) {
    return __builtin_amdgcn_cvt_pk_f32_fp8((int)dw, HI);
}
#else
__device__ __forceinline__ unsigned char fp8_enc(float f) {
    unsigned su = (__float_as_uint(f) >> 24) & 0x80u;
    float af = fminf(fabsf(f), 448.0f);
    unsigned u = __float_as_uint(af);
    int e = (int)((u >> 23) & 255) - 120;
    unsigned b;
    if (e <= 0) b = (unsigned)__float2int_rn(af * 512.0f);
    else {
        unsigned m = (u >> 20) & 7u;
        unsigned rnd = (u >> 19) & 1u;
        b = (((unsigned)e << 3) | m) + rnd;
    }
    b = min(b, 126u);
    return (unsigned char)(su | b);
}
__device__ __forceinline__ float fp8d1(unsigned b) {
    unsigned s = (b & 0x80u) << 24;
    unsigned em = b & 0x7Fu;
    float mag;
    if (em >= 8) mag = __uint_as_float((((em >> 3) + 120u) << 23) | ((em & 7u) << 20));
    else mag = (float)em * 0.001953125f;
    return __uint_as_float(s | __float_as_uint(mag));
}
template <bool HI>
__device__ __forceinline__ f32x2 fp8_dec2(unsigned dw) {
    unsigned w = HI ? (dw >> 16) : dw;
    f32x2 r; r[0] = fp8d1(w & 0xFFu); r[1] = fp8d1((w >> 8) & 0xFFu);
    return r;
}
#endif

// ---------------- one-shot: bf16 B-fragment tables for W_src, W_dst, Wg1 + zero deg
// frag layout: [kb][nt][lane][e] ; value = W[kb*32 + (lane>>4)*8 + e][nt*16 + (lane&15)]
__global__ __launch_bounds__(256) void k_prep(
    const float* __restrict__ Ws, const float* __restrict__ Wd,
    const float* __restrict__ Wg1, short* __restrict__ frag,
    int* __restrict__ deg)
{
    int b = blockIdx.x;
    if (b >= 20) {  // zero-deg portion
        int i = (b - 20) * 256 + threadIdx.x;
        if (i < N_NODES) deg[i] = 0;
        return;
    }
    int g = b * 256 + threadIdx.x;
    if (g >= 5120) return;
    const float* W; short* T; int q;
    if (g < 2048)      { W = Ws;  T = frag;         q = g; }
    else if (g < 4096) { W = Wd;  T = frag + 16384; q = g - 2048; }
    else               { W = Wg1; T = frag + 32768; q = g - 4096; }
    int ls = q & 63, nt = (q >> 6) & 7, kb = q >> 9;
    int col = nt * 16 + (ls & 15);
    int k0 = kb * 32 + (ls >> 4) * 8;
    bf16x8 v;
    #pragma unroll
    for (int e = 0; e < 8; ++e) v[e] = f2bf(W[(k0 + e) * D_MODEL + col]);
    *reinterpret_cast<bf16x8*>(T + (size_t)q * 8) = v;
}

// ---------------- degree count; atomic return value = rank of edge within its dst
__global__ void k_deg(const int* __restrict__ dst, int* __restrict__ deg, int* __restrict__ rank) {
    int e = blockIdx.x * 256 + threadIdx.x;
    if (e < N_EDGES) rank[e] = atomicAdd(&deg[dst[e]], 1);
}

// ---------------- 3-stage exclusive scan -> rstart (with rstart[N]=E sentinel)
__global__ __launch_bounds__(256) void k_scan1(const int* __restrict__ deg, int* __restrict__ bsum) {
    __shared__ int s[256];
    int tid = threadIdx.x;
    int i = blockIdx.x * SCHUNK + tid;
    int v = (tid < SCHUNK && i < N_NODES) ? deg[i] : 0;
    s[tid] = v; __syncthreads();
    for (int off = 128; off > 0; off >>= 1) {
        if (tid < off) s[tid] += s[tid + off];
        __syncthreads();
    }
    if (tid == 0) bsum[blockIdx.x] = s[0];
}
__global__ __launch_bounds__(512) void k_scan2(const int* __restrict__ bsum, int* __restrict__ boff) {
    __shared__ int s[512];
    int tid = threadIdx.x;
    int v = (tid < NSB) ? bsum[tid] : 0;
    s[tid] = v; __syncthreads();
    for (int off = 1; off < 512; off <<= 1) {
        int t = (tid >= off) ? s[tid - off] : 0;
        __syncthreads();
        s[tid] += t;
        __syncthreads();
    }
    if (tid < NSB) boff[tid] = s[tid] - v;
}
__global__ __launch_bounds__(256) void k_scan3(const int* __restrict__ deg, const int* __restrict__ boff,
                                               int* __restrict__ rstart) {
    __shared__ int s[256];
    int tid = threadIdx.x;
    int i = blockIdx.x * SCHUNK + tid;
    int v = (tid < SCHUNK && i < N_NODES) ? deg[i] : 0;
    s[tid] = v; __syncthreads();
    for (int off = 1; off < 256; off <<= 1) {
        int t = (tid >= off) ? s[tid - off] : 0;
        __syncthreads();
        s[tid] += t;
        __syncthreads();
    }
    int excl = s[tid] - v;
    if (tid < SCHUNK && i < N_NODES) {
        rstart[i] = boff[blockIdx.x] + excl;
        if (i == N_NODES - 1) rstart[N_NODES] = boff[blockIdx.x] + excl + v;  // = N_EDGES
    }
}

// ---------------- y_src = fp8(x_src@W_src), z_bf = bf16(x_dst@W_dst + b_dst)
__global__ __launch_bounds__(256, 3) void k_node_linear(
    const float* __restrict__ x_src, const float* __restrict__ x_dst,
    const short* __restrict__ WsrcF, const short* __restrict__ WdstF,
    const float* __restrict__ b_dst,
    unsigned char* __restrict__ ysrc, short* __restrict__ z_bf)
{
    __shared__ __align__(16) short Bf[4][8][64][8];  // 32 KB
    const int tid = threadIdx.x;
    const int lane = tid & 63;
    const int wid = tid >> 6;
    const int l15 = lane & 15;
    const int lg = lane >> 4;
    const int mat = blockIdx.y;
    const float* __restrict__ X = mat ? x_dst : x_src;
    const short* __restrict__ WF = mat ? WdstF : WsrcF;
    const int row0 = blockIdx.x * 128 + wid * 32;

    const float* rowp[2];
    #pragma unroll
    for (int st = 0; st < 2; ++st) {
        int r = min(row0 + st * 16 + l15, N_NODES - 1);
        rowp[st] = X + (size_t)r * D_MODEL + lg * 8;
    }

    float4 buf[2][2][2];
    #pragma unroll
    for (int st = 0; st < 2; ++st) {
        buf[0][st][0] = *reinterpret_cast<const float4*>(rowp[st]);
        buf[0][st][1] = *reinterpret_cast<const float4*>(rowp[st] + 4);
    }

    #pragma unroll
    for (int i = 0; i < 8; ++i)
        reinterpret_cast<int4*>(Bf)[tid + i * 256] =
            reinterpret_cast<const int4*>(WF)[tid + i * 256];

    f32x4 acc[2][8];
    #pragma unroll
    for (int st = 0; st < 2; ++st)
        #pragma unroll
        for (int nt = 0; nt < 8; ++nt) { f32x4 zz = {0.f,0.f,0.f,0.f}; acc[st][nt] = zz; }

    __syncthreads();

    #pragma unroll
    for (int kb = 0; kb < 4; ++kb) {
        if (kb < 3) {
            #pragma unroll
            for (int st = 0; st < 2; ++st) {
                buf[(kb + 1) & 1][st][0] = *reinterpret_cast<const float4*>(rowp[st] + (kb + 1) * 32);
                buf[(kb + 1) & 1][st][1] = *reinterpret_cast<const float4*>(rowp[st] + (kb + 1) * 32 + 4);
            }
        }
        bf16x8 a[2];
        #pragma unroll
        for (int st = 0; st < 2; ++st)
            a[st] = cvt8(buf[kb & 1][st][0], buf[kb & 1][st][1]);
        #pragma unroll
        for (int nt = 0; nt < 8; ++nt) {
            bf16x8 b = *reinterpret_cast<const bf16x8*>(&Bf[kb][nt][lane][0]);
            acc[0][nt] = __builtin_amdgcn_mfma_f32_16x16x32_bf16(a[0], b, acc[0][nt], 0, 0, 0);
            acc[1][nt] = __builtin_amdgcn_mfma_f32_16x16x32_bf16(a[1], b, acc[1][nt], 0, 0, 0);
        }
    }

    #pragma unroll
    for (int st = 0; st < 2; ++st) {
        int rowb = row0 + st * 16 + lg * 4;
        #pragma unroll
        for (int nt = 0; nt < 8; ++nt) {
            int col = nt * 16 + l15;
            float bias = mat ? b_dst[col] : 0.0f;
            #pragma unroll
            for (int r = 0; r < 4; ++r) {
                int row = rowb + r;
                if (row < N_NODES) {
                    float v = acc[st][nt][r];
                    if (mat) z_bf[(size_t)row * D_MODEL + col] = f2bf(v + bias);
                    else     ysrc[(size_t)row * D_MODEL + col] = fp8_enc(v);
                }
            }
        }
    }
}

// ---------------- gate MLP + atomic-free CSR scatter (kb-pipelined A staging)
__global__ __launch_bounds__(256, 5) void k_gate_fill(
    const float* __restrict__ ea, const short* __restrict__ Wg1F,
    const float* __restrict__ bg1, const float* __restrict__ Wg2,
    const float* __restrict__ bg2,
    const int* __restrict__ dstI, const int* __restrict__ srcI,
    const int* __restrict__ rank, const int* __restrict__ rstart,
    int2* __restrict__ sg)
{
    __shared__ __align__(16) short Bf[2][8][64][8];  // 16 KB
    const int tid = threadIdx.x;
    const int lane = tid & 63;
    const int wid = tid >> 6;
    const int l15 = lane & 15;
    const int lg = lane >> 4;
    const int e0 = blockIdx.x * 128 + wid * 32;

    const float* rp[2];
    #pragma unroll
    for (int st = 0; st < 2; ++st) {
        int r = min(e0 + st * 16 + l15, N_EDGES - 1);
        rp[st] = ea + (size_t)r * EDGE_DIM + lg * 8;
    }
    // K-block 0 loads
    float4 b0[2][2];
    #pragma unroll
    for (int st = 0; st < 2; ++st) {
        b0[st][0] = *reinterpret_cast<const float4*>(rp[st]);
        b0[st][1] = *reinterpret_cast<const float4*>(rp[st] + 4);
    }
    // stage Wg1 fragment table
    #pragma unroll
    for (int i = 0; i < 4; ++i)
        reinterpret_cast<int4*>(Bf)[tid + i * 256] =
            reinterpret_cast<const int4*>(Wg1F)[tid + i * 256];
    // K-block 1 loads
    float4 b1[2][2];
    #pragma unroll
    for (int st = 0; st < 2; ++st) {
        b1[st][0] = *reinterpret_cast<const float4*>(rp[st] + 32);
        b1[st][1] = *reinterpret_cast<const float4*>(rp[st] + 36);
    }
    __syncthreads();

    bf16x8 aA[2], aB[2];
    #pragma unroll
    for (int st = 0; st < 2; ++st) aA[st] = cvt8(b0[st][0], b0[st][1]);
    #pragma unroll
    for (int st = 0; st < 2; ++st) aB[st] = cvt8(b1[st][0], b1[st][1]);

    float part[2][4] = {{0.f,0.f,0.f,0.f},{0.f,0.f,0.f,0.f}};
    #pragma unroll
    for (int ntc = 0; ntc < 2; ++ntc) {
        f32x4 acc[2][4];
        #pragma unroll
        for (int st = 0; st < 2; ++st)
            #pragma unroll
            for (int nt = 0; nt < 4; ++nt) { f32x4 zz = {0.f,0.f,0.f,0.f}; acc[st][nt] = zz; }
        #pragma unroll
        for (int nt = 0; nt < 4; ++nt) {
            bf16x8 b = *reinterpret_cast<const bf16x8*>(&Bf[0][ntc * 4 + nt][lane][0]);
            acc[0][nt] = __builtin_amdgcn_mfma_f32_16x16x32_bf16(aA[0], b, acc[0][nt], 0, 0, 0);
            acc[1][nt] = __builtin_amdgcn_mfma_f32_16x16x32_bf16(aA[1], b, acc[1][nt], 0, 0, 0);
        }
        #pragma unroll
        for (int nt = 0; nt < 4; ++nt) {
            bf16x8 b = *reinterpret_cast<const bf16x8*>(&Bf[1][ntc * 4 + nt][lane][0]);
            acc[0][nt] = __builtin_amdgcn_mfma_f32_16x16x32_bf16(aB[0], b, acc[0][nt], 0, 0, 0);
            acc[1][nt] = __builtin_amdgcn_mfma_f32_16x16x32_bf16(aB[1], b, acc[1][nt], 0, 0, 0);
        }
        #pragma unroll
        for (int nt = 0; nt < 4; ++nt) {
            int col = (ntc * 4 + nt) * 16 + l15;
            float b1c = bg1[col];
            float w2 = Wg2[col];
            #pragma unroll
            for (int st = 0; st < 2; ++st)
                #pragma unroll
                for (int r = 0; r < 4; ++r)
                    part[st][r] += gelu_fast(acc[st][nt][r] + b1c) * w2;
        }
    }

    #pragma unroll
    for (int m = 1; m <= 8; m <<= 1)
        #pragma unroll
        for (int st = 0; st < 2; ++st)
            #pragma unroll
            for (int r = 0; r < 4; ++r)
                part[st][r] += __shfl_xor(part[st][r], m);

    if (l15 == 0) {
        float b2 = bg2[0];
        #pragma unroll
        for (int st = 0; st < 2; ++st)
            #pragma unroll
            for (int r = 0; r < 4; ++r) {
                int e = e0 + st * 16 + lg * 4 + r;
                if (e < N_EDGES) {
                    float gv = sigmoid_fast(part[st][r] + b2);
                    int d = dstI[e];
                    int p = rstart[d] + rank[e];
                    int2 v; v.x = srcI[e]; v.y = __float_as_int(gv);
                    sg[p] = v;
                }
            }
    }
}

// ---------------- per-node gather + mean + residual + LN + GELU
// one wave per node; 16 lanes per fp8 edge row (uint2 = 8 fp8/lane), 4 edges in flight
__global__ __launch_bounds__(256) void k_agg(
    const int* __restrict__ rstart, const int2* __restrict__ sg,
    const unsigned char* __restrict__ ysrc, const short* __restrict__ z_bf,
    const float* __restrict__ gamma, const float* __restrict__ beta,
    float* __restrict__ out)
{
    const int lane = threadIdx.x & 63;
    const int wid = threadIdx.x >> 6;
    const int n = blockIdx.x * 4 + wid;
    const int l15 = lane & 15;
    const int lg = lane >> 4;
    const int d0 = l15 * 8;
    const int start = rstart[n];
    const int end = rstart[n + 1];
    const int dg = end - start;

    // node-constant loads issued early
    uint4 zv = *reinterpret_cast<const uint4*>(&z_bf[(size_t)n * D_MODEL + d0]);
    float4 gA = *reinterpret_cast<const float4*>(&gamma[d0]);
    float4 gB = *reinterpret_cast<const float4*>(&gamma[d0 + 4]);
    float4 bA = *reinterpret_cast<const float4*>(&beta[d0]);
    float4 bB = *reinterpret_cast<const float4*>(&beta[d0 + 4]);

    float a[8];
    #pragma unroll
    for (int j = 0; j < 8; ++j) a[j] = 0.f;

    int t = start + lg;
    bool v = t < end;
    int2 eC = make_int2(0, 0); uint2 pC = make_uint2(0, 0);
    if (v) {
        eC = sg[t];
        pC = *reinterpret_cast<const uint2*>(&ysrc[(size_t)eC.x * D_MODEL + d0]);
    }
    while (v) {
        int t2 = t + 4;
        bool v2 = t2 < end;
        int2 eN = make_int2(0, 0); uint2 pN = make_uint2(0, 0);
        if (v2) {
            eN = sg[t2];
            pN = *reinterpret_cast<const uint2*>(&ysrc[(size_t)eN.x * D_MODEL + d0]);
        }
        float g = __int_as_float(eC.y);
        f32x2 q0 = fp8_dec2<false>(pC.x);
        f32x2 q1 = fp8_dec2<true>(pC.x);
        f32x2 q2 = fp8_dec2<false>(pC.y);
        f32x2 q3 = fp8_dec2<true>(pC.y);
        a[0] += g * q0[0]; a[1] += g * q0[1];
        a[2] += g * q1[0]; a[3] += g * q1[1];
        a[4] += g * q2[0]; a[5] += g * q2[1];
        a[6] += g * q3[0]; a[7] += g * q3[1];
        t = t2; eC = eN; pC = pN; v = v2;
    }

    // combine the 4 lg replicas
    #pragma unroll
    for (int j = 0; j < 8; ++j) {
        a[j] += __shfl_xor(a[j], 16);
        a[j] += __shfl_xor(a[j], 32);
    }

    float inv = 1.0f / fmaxf((float)dg, 1.0f);
    float tv[8];
    tv[0] = a[0] * inv + bflo(zv.x); tv[1] = a[1] * inv + bfhi(zv.x);
    tv[2] = a[2] * inv + bflo(zv.y); tv[3] = a[3] * inv + bfhi(zv.y);
    tv[4] = a[4] * inv + bflo(zv.z); tv[5] = a[5] * inv + bfhi(zv.z);
    tv[6] = a[6] * inv + bflo(zv.w); tv[7] = a[7] * inv + bfhi(zv.w);

    float s = 0.f;
    #pragma unroll
    for (int j = 0; j < 8; ++j) s += tv[j];
    #pragma unroll
    for (int m = 1; m <= 8; m <<= 1) s += __shfl_xor(s, m);
    float mu = s * (1.0f / 128.0f);

    float vs = 0.f;
    float dv[8];
    #pragma unroll
    for (int j = 0; j < 8; ++j) { dv[j] = tv[j] - mu; vs += dv[j] * dv[j]; }
    #pragma unroll
    for (int m = 1; m <= 8; m <<= 1) vs += __shfl_xor(vs, m);
    float rstd = rsqrtf(vs * (1.0f / 128.0f) + 1e-5f);

    float o[8];
    o[0] = gelu_fast(dv[0] * rstd * gA.x + bA.x);
    o[1] = gelu_fast(dv[1] * rstd * gA.y + bA.y);
    o[2] = gelu_fast(dv[2] * rstd * gA.z + bA.z);
    o[3] = gelu_fast(dv[3] * rstd * gA.w + bA.w);
    o[4] = gelu_fast(dv[4] * rstd * gB.x + bB.x);
    o[5] = gelu_fast(dv[5] * rstd * gB.y + bB.y);
    o[6] = gelu_fast(dv[6] * rstd * gB.z + bB.z);
    o[7] = gelu_fast(dv[7] * rstd * gB.w + bB.w);

    if (lg == 0) {
        float4 w = make_float4(o[0], o[1], o[2], o[3]);
        *reinterpret_cast<float4*>(&out[(size_t)n * D_MODEL + d0]) = w;
    } else if (lg == 1) {
        float4 w = make_float4(o[4], o[5], o[6], o[7]);
        *reinterpret_cast<float4*>(&out[(size_t)n * D_MODEL + d0 + 4]) = w;
    }
}

extern "C" void kernel_launch(void* const* d_in, const int* in_sizes, int n_in,
                              void* d_out, int out_size, void* d_ws, size_t ws_size,
                              hipStream_t stream)
{
    const float* x_src = (const float*)d_in[0];
    const float* x_dst = (const float*)d_in[1];
    const float* ea    = (const float*)d_in[2];
    const int*   ei    = (const int*)d_in[3];
    const float* W_src = (const float*)d_in[4];
    const float* W_dst = (const float*)d_in[5];
    const float* b_dst = (const float*)d_in[6];
    const float* Wg1   = (const float*)d_in[7];
    const float* bg1   = (const float*)d_in[8];
    const float* Wg2   = (const float*)d_in[9];
    const float* bg2   = (const float*)d_in[10];
    const float* gamma = (const float*)d_in[11];
    const float* beta  = (const float*)d_in[12];
    const int* srcIdx = ei;
    const int* dstIdx = ei + N_EDGES;

    char* ws = (char*)d_ws;
    short*         fragT  = (short*)(ws);                    //     81,920 B
    unsigned char* ysrc   = (unsigned char*)(ws + 81920);    // 12,800,000 B (fp8)
    short*         z_bf   = (short*)(ws + 12881920);         // 25,600,000 B
    int*           deg    = (int*)(ws + 38481920);           //    400,000 B
    int*           rank   = (int*)(ws + 38881920);           //  4,000,000 B
    int*           rstart = (int*)(ws + 42881920);           //    400,004 B
    int2*          sg     = (int2*)(ws + 43281928);          //  8,000,000 B
    int*           bsum   = (int*)(ws + 51281928);           //      1,600 B
    int*           boff   = (int*)(ws + 51283528);           //      1,600 B

    float* out = (float*)d_out;

    hipLaunchKernelGGL(k_prep, dim3(411), dim3(256), 0, stream, W_src, W_dst, Wg1, fragT, deg);
    hipLaunchKernelGGL(k_deg, dim3(3907), dim3(256), 0, stream, dstIdx, deg, rank);
    hipLaunchKernelGGL(k_scan1, dim3(NSB), dim3(256), 0, stream, deg, bsum);
    hipLaunchKernelGGL(k_scan2, dim3(1), dim3(512), 0, stream, bsum, boff);
    hipLaunchKernelGGL(k_scan3, dim3(NSB), dim3(256), 0, stream, deg, boff, rstart);
    hipLaunchKernelGGL(k_node_linear, dim3(782, 2), dim3(256), 0, stream,
                       x_src, x_dst, fragT, fragT + 16384, b_dst, ysrc, z_bf);
    hipLaunchKernelGGL(k_gate_fill, dim3(7813), dim3(256), 0, stream,
                       ea, fragT + 32768, bg1, Wg2, bg2, dstIdx, srcIdx, rank, rstart, sg);
    hipLaunchKernelGGL(k_agg, dim3(N_NODES / 4), dim3(256), 0, stream,
                       rstart, sg, ysrc, z_bf, gamma, beta, out);
}